// Round 13
// baseline (435.921 us; speedup 1.0000x reference)
//
#include <hip/hip_runtime.h>

// Shapes fixed by the reference setup_inputs():
//   x: [B=8, F=512, T=16384] f32 ; out: [8, 16384] f32
#define TT 16384
#define BB 8
#define NB 8        // N_BANDS
#define FB 64       // F / N_BANDS
#define TSM 256     // output cols per block (64 tiles, exact)
#define NTHR 320    // 8 c-groups * 40 spans (5 waves)
#define SPANS 40
#define SPC (SPANS * 8)   // 320 sp cols per band (280 used: TSM + 2*HALO)
#define HALO 12     // pool halo each side: avg(5) + gauss(7)

__device__ __forceinline__ float lgf(float g, float x) {
    // log1p(g*x) with g*x in [0,10): 1+g*x in [1,11) -> fast hw log is safe.
    return __logf(fmaf(g, x, 1.0f));
}

// ---------------- Fused kernel: x -> pool (all 8 bands, t-tile + halo in LDS)
// -> avg11-subtract -> band-mix -> gauss15 -> ReLU -> out + per-block max.
// One block = (batch, 256-col tile). 320 thr = 8 bands x 40 spans x 8 cols.
// Pool phase: per thread, overlapped 12-float register window (3 float4 loads,
// clamped), 64 freq rows, depth-1 prefetch, no barriers. Then 2 LDS phases.
__global__ __launch_bounds__(NTHR) void fused_kernel(
    const float* __restrict__ x,
    const float* __restrict__ log_gamma,
    const float* __restrict__ diff_w,   // [8,1,1,5] flat
    const float* __restrict__ diff_b,   // [8]
    const float* __restrict__ avg_w,    // [8,1,11] flat
    const float* __restrict__ avg_b,    // [8]
    const float* __restrict__ mix_w,    // [1,8] flat
    const float* __restrict__ gauss_w,  // [15]
    const float* __restrict__ gauss_b,  // [1]
    float* __restrict__ out,            // [8,16384] (unnormalized act)
    float* __restrict__ pmax)           // [8*64] per-(batch,tile) maxes
{
    __shared__ float sp[NB][SPC];       // pooled bands, col j -> t = t0-12+j
    __shared__ float sm[TSM + 14];      // x_mix tile, halo 7 each side
    __shared__ float wmax[NTHR / 64];

    const int b   = blockIdx.x >> 6;    // 64 tiles per batch
    const int t0  = (blockIdx.x & 63) * TSM;
    const int tid = threadIdx.x;
    const int c    = tid / SPANS;
    const int span = tid % SPANS;

    const float g  = __expf(log_gamma[c]);
    const float w0 = diff_w[c * 5 + 0], w1 = diff_w[c * 5 + 1],
                w2 = diff_w[c * 5 + 2], w3 = diff_w[c * 5 + 3],
                w4 = diff_w[c * 5 + 4];
    const float bias = diff_b[c];

    const int ts = t0 - HALO + span * 8;       // first output col t of this span
    // load window covers [ts-2, ts+10); clamp base so loads are always valid
    const int  wb    = min(max(ts - 2, 0), TT - 12);
    const int  delta = (ts - 2) - wb;          // 0 interior; !=0 only at edges
    const bool edge  = (delta != 0) || (ts - 2 < 0) || (ts + 10 > TT);
    const float* __restrict__ xr =
        x + ((size_t)b * (NB * FB) + (size_t)c * FB) * TT + wb;

    float acc[8] = {0.f,0.f,0.f,0.f,0.f,0.f,0.f,0.f};

    // prime: row 0's 3 loads
    float4 p0 = *reinterpret_cast<const float4*>(xr);
    float4 p1 = *reinterpret_cast<const float4*>(xr + 4);
    float4 p2 = *reinterpret_cast<const float4*>(xr + 8);

    #pragma unroll 4
    for (int f = 0; f < FB; ++f) {
        const float4 c0 = p0, c1 = p1, c2 = p2;
        // prefetch next row (clamped to last row; stays in-bounds)
        const float* __restrict__ nr = xr + (size_t)((f + 1 < FB) ? f + 1 : f) * TT;
        p0 = *reinterpret_cast<const float4*>(nr);
        p1 = *reinterpret_cast<const float4*>(nr + 4);
        p2 = *reinterpret_cast<const float4*>(nr + 8);

        float lg[12];
        lg[0]=lgf(g,c0.x); lg[1]=lgf(g,c0.y); lg[2] =lgf(g,c0.z); lg[3] =lgf(g,c0.w);
        lg[4]=lgf(g,c1.x); lg[5]=lgf(g,c1.y); lg[6] =lgf(g,c1.z); lg[7] =lgf(g,c1.w);
        lg[8]=lgf(g,c2.x); lg[9]=lgf(g,c2.y); lg[10]=lgf(g,c2.z); lg[11]=lgf(g,c2.w);

        // L[k] = x_log[ts-2+k] with zero padding outside [0,TT)
        float L[12];
        if (!edge) {
            #pragma unroll
            for (int k = 0; k < 12; ++k) L[k] = lg[k];
        } else {
            #pragma unroll
            for (int k = 0; k < 12; ++k) {
                const int tk  = ts - 2 + k;
                const int idx = min(max(k + delta, 0), 11);
                L[k] = ((unsigned)tk < (unsigned)TT) ? lg[idx] : 0.f;
            }
        }

        #pragma unroll
        for (int j = 0; j < 8; ++j) {
            const float d = fmaf(w0, L[j],
                            fmaf(w1, L[j + 1],
                            fmaf(w2, L[j + 2],
                            fmaf(w3, L[j + 3],
                            fmaf(w4, L[j + 4], bias)))));
            acc[j] += (d >= 0.f) ? d : 0.f;    // lrelu, A_LRELU = 0
        }
    }

    // write pooled span to LDS (zero where t outside [0,TT): SAME-pad semantics)
    {
        float* __restrict__ spc = &sp[c][span * 8];
        #pragma unroll
        for (int q = 0; q < 8; ++q) {
            const int t = ts + q;
            spc[q] = ((unsigned)t < (unsigned)TT) ? acc[q] : 0.f;
        }
    }
    __syncthreads();

    // x_mix[m] at t = t0-7+m: sum_c mix_w[c]*(pool_c[t] - avg11(pool_c)[t] - avg_b[c])
    if (tid < TSM + 14) {
        const int t = t0 - 7 + tid;
        float v = 0.f;
        if ((unsigned)t < (unsigned)TT) {     // gauss zero-pads x_mix
            #pragma unroll
            for (int c2 = 0; c2 < NB; ++c2) {
                float av = 0.f;
                #pragma unroll
                for (int j = 0; j < 11; ++j)
                    av = fmaf(avg_w[c2 * 11 + j], sp[c2][tid + j], av);
                const float e = sp[c2][tid + 5] - av - avg_b[c2];
                v = fmaf(mix_w[c2], e, v);
            }
        }
        sm[tid] = v;
    }
    __syncthreads();

    // gauss15 + ReLU + store + block max
    float lmax = 0.f;
    if (tid < TSM) {
        float gs = gauss_b[0];
        #pragma unroll
        for (int k = 0; k < 15; ++k)
            gs = fmaf(gauss_w[k], sm[tid + k], gs);
        const float a = (gs >= 0.f) ? gs : 0.f;   // lrelu, A_LRELU = 0
        out[(size_t)b * TT + t0 + tid] = a;
        lmax = a;
    }
    #pragma unroll
    for (int off = 32; off > 0; off >>= 1)
        lmax = fmaxf(lmax, __shfl_down(lmax, off, 64));
    if ((tid & 63) == 0) wmax[tid >> 6] = lmax;
    __syncthreads();
    if (tid == 0) {
        float m = wmax[0];
        #pragma unroll
        for (int q = 1; q < NTHR / 64; ++q) m = fmaxf(m, wmax[q]);
        pmax[blockIdx.x] = m;
    }
}

// ---------------- Kernel C: reduce 64 tile-maxes per batch, divide by (max + eps)
__global__ __launch_bounds__(256) void norm_kernel(
    float* __restrict__ out, const float* __restrict__ pmax)
{
    const int i = blockIdx.x * 256 + threadIdx.x;   // grid sized exactly B*T/256
    const int b = i >> 14;                          // T = 16384; block-uniform
    const float* __restrict__ pm = pmax + b * 64;   // uniform -> scalar loads
    float m = 0.f;
    #pragma unroll
    for (int k = 0; k < 64; ++k) m = fmaxf(m, pm[k]);
    out[i] = out[i] / (m + 1e-8f);
}

extern "C" void kernel_launch(void* const* d_in, const int* in_sizes, int n_in,
                              void* d_out, int out_size, void* d_ws, size_t ws_size,
                              hipStream_t stream) {
    const float* x        = (const float*)d_in[0];
    const float* log_g    = (const float*)d_in[1];
    const float* diff_w   = (const float*)d_in[2];
    const float* diff_b   = (const float*)d_in[3];
    const float* avg_w    = (const float*)d_in[4];
    const float* avg_b    = (const float*)d_in[5];
    const float* mix_w    = (const float*)d_in[6];
    const float* gauss_w  = (const float*)d_in[7];
    const float* gauss_b  = (const float*)d_in[8];
    float* out = (float*)d_out;

    float* pmax = (float*)d_ws;   // 512 floats

    fused_kernel<<<BB * (TT / TSM), NTHR, 0, stream>>>(
        x, log_g, diff_w, diff_b, avg_w, avg_b, mix_w, gauss_w, gauss_b, out, pmax);
    norm_kernel<<<(BB * TT) / 256, 256, 0, stream>>>(out, pmax);
}